// Round 1
// baseline (108.656 us; speedup 1.0000x reference)
//
#include <hip/hip_runtime.h>
#include <hip/hip_bf16.h>
#include <math.h>

#define NB   256
#define KIN  1024
#define ND   512
#define NP   2048
#define NTOT 4096   // Wm rows + proxy rows stacked

typedef __bf16 bf16x8 __attribute__((ext_vector_type(8)));
typedef float  f32x4  __attribute__((ext_vector_type(4)));
typedef unsigned short ush8 __attribute__((ext_vector_type(8)));

// ws byte offsets (16B aligned)
#define OFF_WPB    0u          // 4096*512 bf16 = 4 MB   (proxy rows pre-scaled by 2)
#define OFF_FEAT32 4194304u    // 256*512 f32   = 512 KB (feat + bias, for row norms)
#define OFF_FEATB  4718592u    // 256*512 bf16  = 256 KB (feat + bias, head A operand)
#define OFF_PN2    4980736u    // 2048 f32      = 8 KB
#define OFF_LOGITS 4988928u    // 256*2048 f32  = 2 MB

__device__ __forceinline__ ush8 pack8(float4 f0, float4 f1) {
    union { ush8 v; __hip_bfloat162 h[4]; } o;
    o.h[0] = __float22bfloat162_rn(make_float2(f0.x, f0.y));
    o.h[1] = __float22bfloat162_rn(make_float2(f0.z, f0.w));
    o.h[2] = __float22bfloat162_rn(make_float2(f1.x, f1.y));
    o.h[3] = __float22bfloat162_rn(make_float2(f1.z, f1.w));
    return o.v;
}
__device__ __forceinline__ unsigned short f2bf(float v) {
    union { __hip_bfloat16 h; unsigned short u; } c;
    c.h = __float2bfloat16(v);
    return c.u;
}

// ---------------------------------------------------------------------------
// K_A: block-specialized fused kernel.
//  blocks 0..31   : feat GEMM 64x64 tile, full K=1024 (no split-K, no atomics)
//                   -> feat32 (f32, +bias) and featb (bf16, +bias)
//  blocks 32..287 : cast Wm (x1) / prox (x2) -> WPb, pn2 = ||prox||^2,
//                   block 32 zeroes the tail accumulators.
// ---------------------------------------------------------------------------
__global__ __launch_bounds__(256) void k_fa(
    const float* __restrict__ x, const float* __restrict__ Wb,
    const float* __restrict__ bb,
    const float* __restrict__ Wm, const float* __restrict__ prox,
    unsigned short* __restrict__ WPb, float* __restrict__ pn2,
    float* __restrict__ feat32, unsigned short* __restrict__ featb,
    float* __restrict__ tail)
{
    __shared__ unsigned short As[2][64 * 32];
    __shared__ unsigned short Bs[2][64 * 32];
    const int t = threadIdx.x, lane = t & 63, w = t >> 6;

    if (blockIdx.x >= 32) {
        // ---------------- prep: cast 16 rows per block ----------------
        const int pb = blockIdx.x - 32;            // 0..255
        if (pb == 0 && t < 2) tail[t] = 0.f;       // zero loss accumulators
#pragma unroll
        for (int i = 0; i < 4; ++i) {
            const int r = pb * 16 + w * 4 + i;     // 0..4095
            const float* src = (r < NP) ? (Wm + (size_t)r * ND)
                                        : (prox + (size_t)(r - NP) * ND);
            float4 v0 = *(const float4*)(src + lane * 8);
            float4 v1 = *(const float4*)(src + lane * 8 + 4);
            if (r < NP) {
                *(ush8*)(WPb + (size_t)r * ND + lane * 8) = pack8(v0, v1);
            } else {
                float s = v0.x*v0.x + v0.y*v0.y + v0.z*v0.z + v0.w*v0.w
                        + v1.x*v1.x + v1.y*v1.y + v1.z*v1.z + v1.w*v1.w;
#pragma unroll
                for (int off = 32; off; off >>= 1) s += __shfl_down(s, off);
                if (lane == 0) pn2[r - NP] = s;
                // store 2*prox so head epilogue is uniformly v +/- cadd.
                // bf16(2v) == 2*bf16(v) exactly (exponent shift).
                float4 d0 = make_float4(v0.x + v0.x, v0.y + v0.y,
                                        v0.z + v0.z, v0.w + v0.w);
                float4 d1 = make_float4(v1.x + v1.x, v1.y + v1.y,
                                        v1.z + v1.z, v1.w + v1.w);
                *(ush8*)(WPb + (size_t)r * ND + lane * 8) = pack8(d0, d1);
            }
        }
        return;
    }

    // ---------------- feat GEMM: 4 m-tiles x 8 n-tiles ----------------
    const int m0 = (blockIdx.x >> 3) * 64, n0 = (blockIdx.x & 7) * 64;
    const int srow = t >> 2, sc = (t & 3) * 8;
    const float* gA = x  + (size_t)(m0 + srow) * KIN + sc;
    const float* gB = Wb + (size_t)(n0 + srow) * KIN + sc;
    float4 a0 = *(const float4*)gA, a1 = *(const float4*)(gA + 4);
    float4 b0 = *(const float4*)gB, b1 = *(const float4*)(gB + 4);
    f32x4 acc[2][2] = {};
    const int wm = (w >> 1) * 32, wn = (w & 1) * 32;
    const int fr = lane & 15, fcol = (lane >> 4) * 8;

    for (int ks = 0; ks < KIN / 32; ++ks) {
        *(ush8*)&As[ks & 1][srow * 32 + sc] = pack8(a0, a1);
        *(ush8*)&Bs[ks & 1][srow * 32 + sc] = pack8(b0, b1);
        __syncthreads();
        if (ks + 1 < KIN / 32) {               // prefetch under MFMAs
            a0 = *(const float4*)(gA + (ks + 1) * 32);
            a1 = *(const float4*)(gA + (ks + 1) * 32 + 4);
            b0 = *(const float4*)(gB + (ks + 1) * 32);
            b1 = *(const float4*)(gB + (ks + 1) * 32 + 4);
        }
        const unsigned short* as = &As[ks & 1][0];
        const unsigned short* bs = &Bs[ks & 1][0];
        bf16x8 af0 = *(const bf16x8*)&as[(wm      + fr) * 32 + fcol];
        bf16x8 af1 = *(const bf16x8*)&as[(wm + 16 + fr) * 32 + fcol];
        bf16x8 bf0 = *(const bf16x8*)&bs[(wn      + fr) * 32 + fcol];
        bf16x8 bf1 = *(const bf16x8*)&bs[(wn + 16 + fr) * 32 + fcol];
        acc[0][0] = __builtin_amdgcn_mfma_f32_16x16x32_bf16(af0, bf0, acc[0][0], 0, 0, 0);
        acc[0][1] = __builtin_amdgcn_mfma_f32_16x16x32_bf16(af0, bf1, acc[0][1], 0, 0, 0);
        acc[1][0] = __builtin_amdgcn_mfma_f32_16x16x32_bf16(af1, bf0, acc[1][0], 0, 0, 0);
        acc[1][1] = __builtin_amdgcn_mfma_f32_16x16x32_bf16(af1, bf1, acc[1][1], 0, 0, 0);
    }

    const int q = lane >> 4;
#pragma unroll
    for (int i = 0; i < 2; ++i)
#pragma unroll
        for (int j = 0; j < 2; ++j) {
            const int n = n0 + wn + 16 * j + fr;
            const float bbn = bb[n];
#pragma unroll
            for (int r = 0; r < 4; ++r) {
                const int m = m0 + wm + 16 * i + q * 4 + r;
                const float v = acc[i][j][r] + bbn;
                feat32[m * ND + n] = v;
                featb [m * ND + n] = f2bf(v);
            }
        }
}

// ---------------------------------------------------------------------------
// K_B: head GEMM, 64x64 tile x 256 blocks. A and B both bf16 -> pure copies
// into LDS (no in-loop cvt/bias). n<2048: out = v + bm ; n>=2048: logits =
// v - pn2 (WPb proxy rows pre-scaled by 2).
// ---------------------------------------------------------------------------
__global__ __launch_bounds__(256) void k_fb(
    const unsigned short* __restrict__ featb,
    const unsigned short* __restrict__ WPb,
    const float* __restrict__ bm, const float* __restrict__ pn2,
    float* __restrict__ out, float* __restrict__ logits)
{
    __shared__ unsigned short As[2][64 * 32];
    __shared__ unsigned short Bs[2][64 * 32];
    const int t = threadIdx.x, lane = t & 63, w = t >> 6;
    const int n0 = blockIdx.x * 64;   // 64 n-tiles over 4096
    const int m0 = blockIdx.y * 64;   // 4 m-tiles over 256
    const int srow = t >> 2, sc = (t & 3) * 8;
    const unsigned short* gA = featb + (size_t)(m0 + srow) * ND + sc;
    const unsigned short* gB = WPb   + (size_t)(n0 + srow) * ND + sc;
    ush8 va = *(const ush8*)gA;
    ush8 vb = *(const ush8*)gB;
    f32x4 acc[2][2] = {};
    const int wm = (w >> 1) * 32, wn = (w & 1) * 32;
    const int fr = lane & 15, fcol = (lane >> 4) * 8;

    for (int ks = 0; ks < ND / 32; ++ks) {
        *(ush8*)&As[ks & 1][srow * 32 + sc] = va;
        *(ush8*)&Bs[ks & 1][srow * 32 + sc] = vb;
        __syncthreads();
        if (ks + 1 < ND / 32) {
            va = *(const ush8*)(gA + (ks + 1) * 32);
            vb = *(const ush8*)(gB + (ks + 1) * 32);
        }
        const unsigned short* as = &As[ks & 1][0];
        const unsigned short* bs = &Bs[ks & 1][0];
        bf16x8 af0 = *(const bf16x8*)&as[(wm      + fr) * 32 + fcol];
        bf16x8 af1 = *(const bf16x8*)&as[(wm + 16 + fr) * 32 + fcol];
        bf16x8 bf0 = *(const bf16x8*)&bs[(wn      + fr) * 32 + fcol];
        bf16x8 bf1 = *(const bf16x8*)&bs[(wn + 16 + fr) * 32 + fcol];
        acc[0][0] = __builtin_amdgcn_mfma_f32_16x16x32_bf16(af0, bf0, acc[0][0], 0, 0, 0);
        acc[0][1] = __builtin_amdgcn_mfma_f32_16x16x32_bf16(af0, bf1, acc[0][1], 0, 0, 0);
        acc[1][0] = __builtin_amdgcn_mfma_f32_16x16x32_bf16(af1, bf0, acc[1][0], 0, 0, 0);
        acc[1][1] = __builtin_amdgcn_mfma_f32_16x16x32_bf16(af1, bf1, acc[1][1], 0, 0, 0);
    }

    const bool isProxy = (n0 >= NP);
    const int q = lane >> 4;
#pragma unroll
    for (int i = 0; i < 2; ++i)
#pragma unroll
        for (int j = 0; j < 2; ++j) {
            const int n = n0 + wn + 16 * j + fr;
            const float cadd = isProxy ? pn2[n - NP] : bm[n];
#pragma unroll
            for (int r = 0; r < 4; ++r) {
                const int m = m0 + wm + 16 * i + q * 4 + r;
                const float v = acc[i][j][r];
                if (isProxy) logits[m * NP + (n - NP)] = v - cadd;
                else         out[m * NP + n] = v + cadd;
            }
        }
}

__device__ __forceinline__ float block_reduce(float v, float* sred, int op)
{
    const int lane = threadIdx.x & 63, wave = threadIdx.x >> 6;
#pragma unroll
    for (int off = 32; off; off >>= 1) {
        float o = __shfl_down(v, off);
        v = op ? fmaxf(v, o) : (v + o);
    }
    if (lane == 0) sred[wave] = v;
    __syncthreads();
    if (threadIdx.x == 0) {
        float r = sred[0];
#pragma unroll
        for (int wv = 1; wv < 4; ++wv) r = op ? fmaxf(r, sred[wv]) : (r + sred[wv]);
        sred[0] = r;
    }
    __syncthreads();
    float r = sred[0];
    __syncthreads();
    return r;
}

// K_C: per-row logsumexp + gather + feat row norm, accumulated straight into
// the two output tail scalars (replaces rowlp/rownm buffers + k_final).
__global__ __launch_bounds__(256) void k_fc(
    const float* __restrict__ feat32, const float* __restrict__ logits,
    const int* __restrict__ y, float* __restrict__ tail)
{
    __shared__ float sred[4];
    const int b = blockIdx.x, t = threadIdx.x;

    float v0 = feat32[b * ND + t];           // bias already folded in
    float v1 = feat32[b * ND + t + 256];
    float fn2 = block_reduce(v0 * v0 + v1 * v1, sred, 0);

    const float* lr = logits + (size_t)b * NP;
    float lv[8], mx = -INFINITY;
#pragma unroll
    for (int j = 0; j < 8; ++j) { lv[j] = lr[t + 256 * j]; mx = fmaxf(mx, lv[j]); }
    float MX = block_reduce(mx, sred, 1);
    float es = 0.f;
#pragma unroll
    for (int j = 0; j < 8; ++j) es += __expf(lv[j] - MX);
    float SUM = block_reduce(es, sred, 0);

    if (t == 0) {
        float ly = lr[y[b]];
        float lp = ly - MX - __logf(SUM);
        atomicAdd(&tail[0], -lp * (1.0f / (float)NB));
        atomicAdd(&tail[1], sqrtf(fn2) * (1.0f / (float)NB));
    }
}

extern "C" void kernel_launch(void* const* d_in, const int* in_sizes, int n_in,
                              void* d_out, int out_size, void* d_ws, size_t ws_size,
                              hipStream_t stream)
{
    const float* x       = (const float*)d_in[0];
    const int*   y       = (const int*)  d_in[1];
    const float* Wb      = (const float*)d_in[2];
    const float* bb      = (const float*)d_in[3];
    const float* Wm      = (const float*)d_in[4];
    const float* bm      = (const float*)d_in[5];
    const float* proxies = (const float*)d_in[6];

    char* ws = (char*)d_ws;
    unsigned short* WPb    = (unsigned short*)(ws + OFF_WPB);
    float*          feat32 = (float*)(ws + OFF_FEAT32);
    unsigned short* featb  = (unsigned short*)(ws + OFF_FEATB);
    float*          pn2    = (float*)(ws + OFF_PN2);
    float*          logits = (float*)(ws + OFF_LOGITS);

    float* out  = (float*)d_out;
    float* tail = out + (size_t)NB * NP;

    k_fa<<<dim3(288), dim3(256), 0, stream>>>(
        x, Wb, bb, Wm, proxies, WPb, pn2, feat32, featb, tail);
    k_fb<<<dim3(NTOT / 64, NB / 64), dim3(256), 0, stream>>>(
        featb, WPb, bm, pn2, out, logits);
    k_fc<<<dim3(NB), dim3(256), 0, stream>>>(feat32, logits, y, tail);
}